// Round 13
// baseline (489.350 us; speedup 1.0000x reference)
//
#include <hip/hip_runtime.h>
#include <stdint.h>
#include <stddef.h>

typedef float f32x4 __attribute__((ext_vector_type(4)));
typedef __bf16 bf16x8 __attribute__((ext_vector_type(8)));
typedef short s16x4 __attribute__((ext_vector_type(4)));

#define DEVI static __device__ __forceinline__

DEVI float bf2f(unsigned short u) {
  unsigned int x = ((unsigned int)u) << 16;
  float f;
  __builtin_memcpy(&f, &x, 4);
  return f;
}
DEVI unsigned short f2bf(float f) {
  unsigned int x;
  __builtin_memcpy(&x, &f, 4);
  unsigned int r = (x + 0x7fffu + ((x >> 16) & 1u)) >> 16;
  return (unsigned short)r;
}

DEVI void async16(const void* g, void* l) {
  __builtin_amdgcn_global_load_lds((__attribute__((address_space(1))) void*)g,
                                   (__attribute__((address_space(3))) void*)l,
                                   16, 0, 0);
}

// raw barrier with own-LDS-ops drain; vmcnt NOT touched.
#define BAR_LGKM()                                          \
  do {                                                      \
    asm volatile("s_waitcnt lgkmcnt(0)" ::: "memory");      \
    __builtin_amdgcn_s_barrier();                           \
    __builtin_amdgcn_sched_barrier(0);                      \
  } while (0)

// counted-vmcnt barrier: N loads may stay in flight (T4).
#define BAR_VM(N)                                               \
  do {                                                          \
    asm volatile("s_waitcnt vmcnt(" #N ")" ::: "memory");       \
    __builtin_amdgcn_s_barrier();                               \
    __builtin_amdgcn_sched_barrier(0);                          \
  } while (0)

// ---------------- fp32 -> bf16 conversion ----------------
__global__ __launch_bounds__(256) void cvt_bf16(const float* __restrict__ in,
                                                unsigned short* __restrict__ out, int n) {
  int i = (blockIdx.x * 256 + threadIdx.x) * 4;
  if (i >= n) return;
  float4 v = *(const float4*)(in + i);
  s16x4 o;
  o[0] = (short)f2bf(v.x);
  o[1] = (short)f2bf(v.y);
  o[2] = (short)f2bf(v.z);
  o[3] = (short)f2bf(v.w);
  *(s16x4*)(out + i) = o;
}

// ---------------- RoPE table: tab[t][0..63]=cos, tab[t][64..127]=sin ----------------
__global__ __launch_bounds__(256) void rope_table(float* __restrict__ tab) {
  int idx = blockIdx.x * 256 + threadIdx.x;
  if (idx >= 2048 * 64) return;
  int tt = idx >> 6, j = idx & 63;
  float inv = powf(10000.0f, -(float)j * (1.0f / 64.0f));
  float ang = (float)tt * inv;
  tab[tt * 128 + j] = cosf(ang);
  tab[tt * 128 + 64 + j] = sinf(ang);
}

// ---------------- RoPE apply, vectorized x4; Q pre-scaled by 1/sqrt(hd)*log2(e) ----
__global__ __launch_bounds__(256) void rope_apply(unsigned short* __restrict__ Qg,
                                                  unsigned short* __restrict__ Kg,
                                                  const float* __restrict__ tab) {
  const float S2 = 0.0883883476483184f * 1.44269504088896341f;
  int idx = blockIdx.x * 256 + threadIdx.x;  // bh*2048*16 + tt*16 + j4
  int j4 = idx & 15;
  int tt = (idx >> 4) & 2047;
  int bh = idx >> 15;
  size_t base = ((size_t)bh * 2048 + tt) * 128;
  f32x4 c4 = *(const f32x4*)(tab + tt * 128 + j4 * 4);
  f32x4 s4 = *(const f32x4*)(tab + tt * 128 + 64 + j4 * 4);
  s16x4 q1 = *(const s16x4*)(Qg + base + j4 * 4);
  s16x4 q2 = *(const s16x4*)(Qg + base + 64 + j4 * 4);
  s16x4 k1 = *(const s16x4*)(Kg + base + j4 * 4);
  s16x4 k2 = *(const s16x4*)(Kg + base + 64 + j4 * 4);
  s16x4 o1, o2, p1, p2;
#pragma unroll
  for (int r = 0; r < 4; ++r) {
    float c = c4[r], s = s4[r];
    float a = bf2f((unsigned short)q1[r]), b2 = bf2f((unsigned short)q2[r]);
    o1[r] = (short)f2bf((a * c - b2 * s) * S2);
    o2[r] = (short)f2bf((a * s + b2 * c) * S2);
    float ka = bf2f((unsigned short)k1[r]), kb = bf2f((unsigned short)k2[r]);
    p1[r] = (short)f2bf(ka * c - kb * s);
    p2[r] = (short)f2bf(ka * s + kb * c);
  }
  *(s16x4*)(Qg + base + j4 * 4) = o1;
  *(s16x4*)(Qg + base + 64 + j4 * 4) = o2;
  *(s16x4*)(Kg + base + j4 * 4) = p1;
  *(s16x4*)(Kg + base + 64 + j4 * 4) = p2;
}

// ---------------- 256x256 4-phase GEMM: C[m][n] = sum_k A[m][k]*B[n][k] ----------------
// R13: 4 phases/iter (phase = tile x M-half), full-N MFMA cluster per phase
// (4mf x 4nf x 2kk = 32 MFMA). B-frags (8 ds_read) loaded once per tile, held
// in regs across the mh pair; A-frags 8 ds_read per phase. 8 barriers/iter
// (was 16). Region lifetimes: Bl[p]+Al[p][0] free after tile's first phase,
// Al[p][1] after its second. Stages: P0: A(1,h1,t1); P1: B(0,h0,t2),B(0,h1,t2),
// A(0,h0,t2); P2: A(0,h1,t2); P3: B(1,h0,t3),B(1,h1,t3),A(1,h0,t3).
// FIFO (in-flight 14/10/14): vmcnt(8)@P1, vmcnt(8)@P2, vmcnt(6)@P3; last iter
// vmcnt(2)/vmcnt(0). Layout: 128B rows, unit swizzle (t&7)^(row&7) both sides
// (measured 0 conflicts).
template <int EPI>
__global__ __launch_bounds__(512) void gemm256(const unsigned short* __restrict__ A,
                                               const unsigned short* __restrict__ B,
                                               float* __restrict__ C, int M, int N, int K,
                                               unsigned short* __restrict__ Q,
                                               unsigned short* __restrict__ Kk,
                                               unsigned short* __restrict__ VT) {
  __shared__ __attribute__((aligned(128))) unsigned short Al[2][2][8192];
  __shared__ __attribute__((aligned(128))) unsigned short Bl[2][2][8192];
  const int t = threadIdx.x;
  const int lane = t & 63;
  const int w = t >> 6, wr = w >> 2, wc = w & 3;
  const int g = lane >> 4, lr = lane & 15;

  const int id = blockIdx.y * gridDim.x + blockIdx.x;
  const int nwg = gridDim.x * gridDim.y;
  const int wg = (id & 7) * (nwg >> 3) + (id >> 3);  // XCD-chunked (nwg%8==0)
  const int bm = (wg / gridDim.x) * 256, bn = (wg % gridDim.x) * 256;

  const unsigned short* aptr = A + (size_t)bm * K;
  const unsigned short* bptr = B + (size_t)bn * K;

  const int srow = t >> 3;                 // 0..63
  const int sslot = (t & 7) ^ (srow & 7);  // inverse-swizzled source 16B slot

#define STG(arr, mat, p, h, kt)                                                   \
  do {                                                                            \
    const unsigned short* _s =                                                    \
        (mat) + (size_t)((h) * 128 + srow) * K + (size_t)(kt) * 64 + sslot * 8;   \
    async16(_s, &arr[p][h][t * 8]);                                               \
    async16(_s + (size_t)64 * K, &arr[p][h][t * 8 + 4096]);                       \
  } while (0)

  const int u0 = ((g ^ (lr & 7)) * 8) + lr * 64;
  const int u1 = (((4 + g) ^ (lr & 7)) * 8) + lr * 64;

  // A-frags for phase (p, mh): row wr*128 + mh*64 + mf*16 + lr
#define LDA_(p, mh)                                                               \
  _Pragma("unroll") for (int mf = 0; mf < 4; ++mf) {                              \
    af[mf][0] = *(const bf16x8*)&Al[p][wr][(mh) * 4096 + mf * 1024 + u0];         \
    af[mf][1] = *(const bf16x8*)&Al[p][wr][(mh) * 4096 + mf * 1024 + u1];         \
  }
  // B-frags, FULL N (4 nf): row wc*64 + nf*16 + lr -> half wc>>1, off (wc&1)*4096
#define LDB_(p)                                                                   \
  _Pragma("unroll") for (int nf = 0; nf < 4; ++nf) {                              \
    bfr[nf][0] = *(const bf16x8*)&Bl[p][wc >> 1][(wc & 1) * 4096 + nf * 1024 + u0]; \
    bfr[nf][1] = *(const bf16x8*)&Bl[p][wc >> 1][(wc & 1) * 4096 + nf * 1024 + u1]; \
  }
#define MMA_(mh)                                                                  \
  __builtin_amdgcn_s_setprio(1);                                                  \
  _Pragma("unroll") for (int mf = 0; mf < 4; ++mf)                                \
      _Pragma("unroll") for (int nf = 0; nf < 4; ++nf) {                          \
    acc[(mh) * 4 + mf][nf] = __builtin_amdgcn_mfma_f32_16x16x32_bf16(             \
        af[mf][0], bfr[nf][0], acc[(mh) * 4 + mf][nf], 0, 0, 0);                  \
    acc[(mh) * 4 + mf][nf] = __builtin_amdgcn_mfma_f32_16x16x32_bf16(             \
        af[mf][1], bfr[nf][1], acc[(mh) * 4 + mf][nf], 0, 0, 0);                  \
  }                                                                               \
  __builtin_amdgcn_s_setprio(0);
#define BARR() __builtin_amdgcn_s_barrier();

  f32x4 acc[8][4] = {};
  bf16x8 af[4][2], bfr[4][2];

  // prologue: t0's 4 halves (8 loads, oldest), then t1's {B h0, B h1, A h0} (6).
  STG(Al, aptr, 0, 0, 0);
  STG(Al, aptr, 0, 1, 0);
  STG(Bl, bptr, 0, 0, 0);
  STG(Bl, bptr, 0, 1, 0);
  STG(Bl, bptr, 1, 0, 1);
  STG(Bl, bptr, 1, 1, 1);
  STG(Al, aptr, 1, 0, 1);
  asm volatile("s_waitcnt vmcnt(6)" ::: "memory");  // t0's 8 loads landed
  __builtin_amdgcn_s_barrier();

  const int NITER = K >> 7;
  for (int i = 0; i < NITER; ++i) {
    const bool G = (i + 1 < NITER);
    const int t1 = 2 * i + 1, t2 = 2 * i + 2, t3 = 2 * i + 3;

    // P0: tile 2i, mh0. Stage A(1,h1,t1) (Al[1][1] last read prev-P3, 1 barrier ago).
    LDA_(0, 0);
    LDB_(0);
    STG(Al, aptr, 1, 1, t1);
    BARR();
    MMA_(0);
    BARR();
    // P1: mh1 (B reused in regs). Stage B(0,*,t2)+A(0,h0,t2) (free after P0).
    // vmcnt(8): drains prev-P3's 6 (t1's B+A.h0) before P2 reads them.
    LDA_(0, 1);
    if (G) {
      STG(Bl, bptr, 0, 0, t2);
      STG(Bl, bptr, 0, 1, t2);
      STG(Al, aptr, 0, 0, t2);
      asm volatile("s_waitcnt vmcnt(8)" ::: "memory");
    } else {
      asm volatile("s_waitcnt vmcnt(2)" ::: "memory");
    }
    BARR();
    MMA_(1);
    BARR();
    // P2: tile 2i+1, mh0. Stage A(0,h1,t2) (Al[0][1] free after P1).
    // vmcnt(8): drains P0's 2 (t1's A.h1) before P3 reads it.
    LDA_(1, 0);
    LDB_(1);
    if (G) {
      STG(Al, aptr, 0, 1, t2);
      asm volatile("s_waitcnt vmcnt(8)" ::: "memory");
    } else {
      asm volatile("s_waitcnt vmcnt(0)" ::: "memory");
    }
    BARR();
    MMA_(0);
    BARR();
    // P3: mh1 (B reused). Stage B(1,*,t3)+A(1,h0,t3) (Bl[1] free after P2,
    // Al[1][0] free after P2). vmcnt(6): drains t2's 8 (P1's 6 + P2's 2)
    // before next-P0 reads them.
    LDA_(1, 1);
    if (G) {
      STG(Bl, bptr, 1, 0, t3);
      STG(Bl, bptr, 1, 1, t3);
      STG(Al, aptr, 1, 0, t3);
      asm volatile("s_waitcnt vmcnt(6)" ::: "memory");
    }
    BARR();
    MMA_(1);
    BARR();
  }
#undef STG
#undef LDA_
#undef LDB_
#undef MMA_
#undef BARR

  // epilogue: acc[mh*4+mf][nf]: row off = (mp>>2)*64+(mp&3)*16+g*4, col nf*16+lr.
  if (EPI == 0) {
#pragma unroll
    for (int mp = 0; mp < 8; ++mp) {
      int m0 = bm + wr * 128 + (mp >> 2) * 64 + (mp & 3) * 16 + g * 4;
#pragma unroll
      for (int nf = 0; nf < 4; ++nf) {
        int n = bn + wc * 64 + nf * 16 + lr;
#pragma unroll
        for (int r = 0; r < 4; ++r) C[(size_t)(m0 + r) * N + n] = acc[mp][nf][r];
      }
    }
  } else {
    const int bi = bm >> 11;
    const int tbase = bm & 2047;
#pragma unroll
    for (int nf = 0; nf < 4; ++nf) {
      int e = bn + wc * 64 + nf * 16 + lr;  // region uniform per block
      int region = e >> 11;
      int e2 = e & 2047;
      int h = e2 >> 7, d = e2 & 127;
      int bh = bi * 16 + h;
#pragma unroll
      for (int mp = 0; mp < 8; ++mp) {
        int trow = tbase + wr * 128 + (mp >> 2) * 64 + (mp & 3) * 16 + g * 4;
        if (region == 2) {
          s16x4 pk;
#pragma unroll
          for (int r = 0; r < 4; ++r) pk[r] = (short)f2bf(acc[mp][nf][r]);
          *(s16x4*)(VT + ((size_t)bh * 128 + d) * 2048 + trow) = pk;
        } else {
          unsigned short* dst = (region == 0) ? Q : Kk;
#pragma unroll
          for (int r = 0; r < 4; ++r)
            dst[((size_t)bh * 2048 + trow + r) * 128 + d] = f2bf(acc[mp][nf][r]);
        }
      }
    }
  }
}

// ---------------- flash attention (R8, unchanged) ----------------
__global__ __launch_bounds__(256) void flash_attn(const unsigned short* __restrict__ Qg,
                                                  const unsigned short* __restrict__ Kg,
                                                  const unsigned short* __restrict__ VTg,
                                                  unsigned short* __restrict__ Yg,
                                                  const int* __restrict__ iscausal,
                                                  const unsigned char* __restrict__ amask) {
  __shared__ __attribute__((aligned(128))) unsigned short Ks[2][64 * 128];
  __shared__ __attribute__((aligned(128))) unsigned short Vs[2][128 * 64];
  __shared__ __attribute__((aligned(128))) unsigned short Ps[4][16 * 72];

  const int t = threadIdx.x, lane = t & 63, w = t >> 6;
  const int g = lane >> 4, lr = lane & 15;
  const int id = blockIdx.x;
  const int xcd = id & 7, j5 = id >> 3;
  const int bh = xcd * 8 + (j5 >> 5);
  const int qbi = 31 - (j5 & 31);
  const int b = bh >> 4;
  const int qb = qbi * 64;
  const int causal = iscausal[0] != 0;
  const int nt = causal ? (qbi + 1) : 32;

  const unsigned short* qrow = Qg + ((size_t)bh * 2048 + qb + w * 16 + lr) * 128;
  bf16x8 qf[4];
#pragma unroll
  for (int ds = 0; ds < 4; ++ds) qf[ds] = *(const bf16x8*)(qrow + ds * 32 + g * 8);

  const unsigned short* Kbase = Kg + (size_t)bh * 2048 * 128;
  const unsigned short* Vbase = VTg + (size_t)bh * 128 * 2048;

  const int rK = t >> 4, sK = ((t & 15) ^ rK);
  const int rV = t >> 3, sV = ((t & 7) ^ ((t >> 3) & 7));

#define STAGE(KT, P)                                                                    \
  do {                                                                                  \
    const int _kv = (KT) * 64;                                                          \
    _Pragma("unroll") for (int c = 0; c < 4; ++c)                                       \
        async16(Kbase + (size_t)(_kv + c * 16 + rK) * 128 + sK * 8,                     \
                &Ks[P][c * 2048 + t * 8]);                                              \
    _Pragma("unroll") for (int c = 0; c < 4; ++c)                                       \
        async16(Vbase + (size_t)(c * 32 + rV) * 2048 + _kv + sV * 8,                    \
                &Vs[P][c * 2048 + t * 8]);                                              \
  } while (0)

  unsigned int oi[4] = {0x3F803F80u, 0x3F803F80u, 0x3F803F80u, 0x3F803F80u};
  bf16x8 ones;
  __builtin_memcpy(&ones, oi, 16);

  f32x4 acc[8] = {};
  f32x4 accl = {0.f, 0.f, 0.f, 0.f};
  float mrow[4] = {-1e30f, -1e30f, -1e30f, -1e30f};

  STAGE(0, 0);

  for (int kt = 0; kt < nt; ++kt) {
    const int p = kt & 1;
    const int kv0 = kt * 64;
    if (kt + 1 < nt) {
      STAGE(kt + 1, p ^ 1);
      BAR_VM(8);
    } else {
      BAR_VM(0);
    }

    f32x4 s[4] = {};
    __builtin_amdgcn_s_setprio(1);
#pragma unroll
    for (int cf = 0; cf < 4; ++cf)
#pragma unroll
      for (int ds = 0; ds < 4; ++ds) {
        bf16x8 kf = *(const bf16x8*)(&Ks[p][(cf * 16 + lr) * 128 + (((ds * 4 + g) ^ lr) * 8)]);
        s[cf] = __builtin_amdgcn_mfma_f32_16x16x32_bf16(qf[ds], kf, s[cf], 0, 0, 0);
      }
    __builtin_amdgcn_s_setprio(0);

    const int q0 = qb + w * 16 + g * 4;
    if (causal) {
      if (kt == qbi) {
#pragma unroll
        for (int cf = 0; cf < 4; ++cf) {
          int kvg = kv0 + cf * 16 + lr;
#pragma unroll
          for (int r = 0; r < 4; ++r)
            if (kvg > q0 + r) s[cf][r] = -1e30f;
        }
      }
    } else {
#pragma unroll
      for (int cf = 0; cf < 4; ++cf) {
        int kvg = kv0 + cf * 16 + lr;
        if (!amask[(size_t)b * 2048 + kvg]) {
#pragma unroll
          for (int r = 0; r < 4; ++r) s[cf][r] = -1e30f;
        }
      }
    }

    f32x4 lm;
#pragma unroll
    for (int r = 0; r < 4; ++r)
      lm[r] = fmaxf(fmaxf(s[0][r], s[1][r]), fmaxf(s[2][r], s[3][r]));
    bool ok = true;
#pragma unroll
    for (int r = 0; r < 4; ++r) ok = ok && (lm[r] <= mrow[r] + 8.0f);
    if (!__all(ok)) {
      f32x4 mx = lm;
#pragma unroll
      for (int off = 8; off >= 1; off >>= 1)
#pragma unroll
        for (int r = 0; r < 4; ++r) mx[r] = fmaxf(mx[r], __shfl_xor(mx[r], off));
#pragma unroll
      for (int r = 0; r < 4; ++r) {
        float mn = fmaxf(mrow[r], mx[r]);
        float corr = exp2f(mrow[r] - mn);
        mrow[r] = mn;
        accl[r] *= corr;
#pragma unroll
        for (int jf = 0; jf < 8; ++jf) acc[jf][r] *= corr;
      }
    }

#pragma unroll
    for (int cf = 0; cf < 4; ++cf)
#pragma unroll
      for (int r = 0; r < 4; ++r) s[cf][r] = exp2f(s[cf][r] - mrow[r]);

    unsigned short* Pw = &Ps[w][0];
#pragma unroll
    for (int cf = 0; cf < 4; ++cf)
#pragma unroll
      for (int r = 0; r < 4; ++r) Pw[(g * 4 + r) * 72 + cf * 16 + lr] = f2bf(s[cf][r]);
    asm volatile("s_waitcnt lgkmcnt(0)" ::: "memory");
    __builtin_amdgcn_sched_barrier(0);

    bf16x8 pa0 = *(const bf16x8*)(Pw + lr * 72 + g * 8);
    bf16x8 pa1 = *(const bf16x8*)(Pw + lr * 72 + 32 + g * 8);

    accl = __builtin_amdgcn_mfma_f32_16x16x32_bf16(pa0, ones, accl, 0, 0, 0);
    accl = __builtin_amdgcn_mfma_f32_16x16x32_bf16(pa1, ones, accl, 0, 0, 0);

    __builtin_amdgcn_s_setprio(1);
#pragma unroll
    for (int jf = 0; jf < 8; ++jf) {
      bf16x8 v0 = *(const bf16x8*)(&Vs[p][(jf * 16 + lr) * 64 + ((g ^ (lr & 7)) * 8)]);
      bf16x8 v1 = *(const bf16x8*)(&Vs[p][(jf * 16 + lr) * 64 + (((4 + g) ^ (lr & 7)) * 8)]);
      acc[jf] = __builtin_amdgcn_mfma_f32_16x16x32_bf16(pa0, v0, acc[jf], 0, 0, 0);
      acc[jf] = __builtin_amdgcn_mfma_f32_16x16x32_bf16(pa1, v1, acc[jf], 0, 0, 0);
    }
    __builtin_amdgcn_s_setprio(0);

    BAR_LGKM();
  }
#undef STAGE

  const int h = bh & 15;
  float rl[4];
#pragma unroll
  for (int r = 0; r < 4; ++r) rl[r] = __builtin_amdgcn_rcpf(accl[r]);
#pragma unroll
  for (int jf = 0; jf < 8; ++jf)
#pragma unroll
    for (int r = 0; r < 4; ++r) {
      int tt = qb + w * 16 + g * 4 + r;
      Yg[((size_t)b * 2048 + tt) * 2048 + h * 128 + jf * 16 + lr] = f2bf(acc[jf][r] * rl[r]);
    }
}

// ---------------- launch ----------------
extern "C" void kernel_launch(void* const* d_in, const int* in_sizes, int n_in, void* d_out,
                              int out_size, void* d_ws, size_t ws_size, hipStream_t stream) {
  const float* x = (const float*)d_in[0];
  const unsigned char* amask = (const unsigned char*)d_in[1];
  const int* iscausal = (const int*)d_in[2];
  const float* wqkv = (const float*)d_in[3];
  const float* wout = (const float*)d_in[4];
  float* out = (float*)d_out;

  const size_t MT = 8192, D = 2048, ND = 6144;
  unsigned short* xb = (unsigned short*)d_ws;
  unsigned short* wqkvb = xb + MT * D;
  unsigned short* woutb = wqkvb + ND * D;
  unsigned short* q = woutb + D * D;
  unsigned short* k = q + MT * D;
  unsigned short* vt = k + MT * D;
  unsigned short* y = vt + MT * D;
  float* tab = (float*)(y + MT * D);
  if (ws_size < (size_t)(100663296) * 2 + 2048 * 128 * 4) return;

  cvt_bf16<<<dim3(16384), dim3(256), 0, stream>>>(x, xb, (int)(MT * D));
  cvt_bf16<<<dim3(12288), dim3(256), 0, stream>>>(wqkv, wqkvb, (int)(ND * D));
  cvt_bf16<<<dim3(4096), dim3(256), 0, stream>>>(wout, woutb, (int)(D * D));
  rope_table<<<dim3(512), dim3(256), 0, stream>>>(tab);
  gemm256<1><<<dim3(24, 32), dim3(512), 0, stream>>>(xb, wqkvb, nullptr, 8192, 6144, 2048, q, k, vt);
  rope_apply<<<dim3(8192), dim3(256), 0, stream>>>(q, k, tab);
  flash_attn<<<dim3(2048), dim3(256), 0, stream>>>(q, k, vt, y, iscausal, amask);
  gemm256<0><<<dim3(8, 32), dim3(512), 0, stream>>>(y, woutb, out, 8192, 2048, 2048, nullptr,
                                                    nullptr, nullptr);
}